// Round 1
// baseline (164.356 us; speedup 1.0000x reference)
//
#include <hip/hip_runtime.h>

#define Vv 30
#define Tt 8192
#define Kk 5
#define Ll 512
#define Bb 32
#define NVK (Vv * Kk)      // 150 real rows
#define ZROW NVK           // row 150 = zeros (for out-of-range neighbors)
#define NROWS (NVK + 1)    // 151 rows in workspace

// ---------------------------------------------------------------------------
// Kernel 1: transpose conv_w (T,V,K) -> wt[vk][t], fold bias into k==2 rows,
// and write the zero row. Grid: T/32 = 256 blocks x 256 threads.
// ---------------------------------------------------------------------------
__global__ __launch_bounds__(256) void transpose_w(
    const float* __restrict__ conv_w,
    const float* __restrict__ conv_b,
    float* __restrict__ wt)
{
    const int TILE = 32;
    __shared__ float tile[TILE * NVK];   // 32*150*4 = 19.2 KB

    const int t0 = blockIdx.x * TILE;

    // Coalesced flat copy of 32 consecutive conv_w rows (t-major source).
    for (int i = threadIdx.x; i < TILE * NVK; i += 256)
        tile[i] = conv_w[t0 * NVK + i];
    __syncthreads();

    // Transposed write: wt[vk*T + t], coalesced in 32-float chunks.
    for (int i = threadIdx.x; i < NVK * TILE; i += 256) {
        const int vk = i >> 5;    // 0..149
        const int tl = i & 31;
        float v = tile[tl * NVK + vk];
        const int k = vk - (vk / Kk) * Kk;
        if (k == 2) v += conv_b[t0 + tl];   // fold bias (k==2 always in-range)
        wt[vk * Tt + t0 + tl] = v;
    }

    // Zero row for out-of-range neighbors.
    if (threadIdx.x < TILE)
        wt[ZROW * Tt + t0 + threadIdx.x] = 0.0f;
}

// ---------------------------------------------------------------------------
// Kernel 2: per-position 5-row gather-sum + argmax over T.
// Grid: 16384 blocks (one per (b,l)) x 256 threads.
// ---------------------------------------------------------------------------
__global__ __launch_bounds__(256) void conv_argmax(
    const int* __restrict__ seq,
    const float* __restrict__ wt,
    int* __restrict__ out)
{
    const int pos = blockIdx.x;
    const int b = pos >> 9;          // / L
    const int l = pos & (Ll - 1);    // % L

    // Row index per tap; out-of-range -> zero row.
    int rows[Kk];
#pragma unroll
    for (int k = 0; k < Kk; ++k) {
        const int lp = l + k - Kk / 2;
        rows[k] = (lp >= 0 && lp < Ll) ? (seq[b * Ll + lp] * Kk + k) : ZROW;
    }

    const float4* __restrict__ p0 = (const float4*)(wt + (size_t)rows[0] * Tt);
    const float4* __restrict__ p1 = (const float4*)(wt + (size_t)rows[1] * Tt);
    const float4* __restrict__ p2 = (const float4*)(wt + (size_t)rows[2] * Tt);
    const float4* __restrict__ p3 = (const float4*)(wt + (size_t)rows[3] * Tt);
    const float4* __restrict__ p4 = (const float4*)(wt + (size_t)rows[4] * Tt);

    const int tid = threadIdx.x;
    float bv = -1e30f;
    int   bt = 0;

#pragma unroll
    for (int i = 0; i < Tt / 4 / 256; ++i) {   // 8 iterations
        const int idx = i * 256 + tid;
        const float4 a = p0[idx];
        const float4 c = p1[idx];
        const float4 d = p2[idx];
        const float4 e = p3[idx];
        const float4 f = p4[idx];
        const float s0 = a.x + c.x + d.x + e.x + f.x;
        const float s1 = a.y + c.y + d.y + e.y + f.y;
        const float s2 = a.z + c.z + d.z + e.z + f.z;
        const float s3 = a.w + c.w + d.w + e.w + f.w;
        const int t = idx * 4;
        if (s0 > bv) { bv = s0; bt = t; }
        if (s1 > bv) { bv = s1; bt = t + 1; }
        if (s2 > bv) { bv = s2; bt = t + 2; }
        if (s3 > bv) { bv = s3; bt = t + 3; }
    }

    // Wave (64-lane) argmax reduce; first-index tie-break.
#pragma unroll
    for (int off = 32; off >= 1; off >>= 1) {
        const float ov = __shfl_down(bv, off);
        const int   ot = __shfl_down(bt, off);
        if (ov > bv || (ov == bv && ot < bt)) { bv = ov; bt = ot; }
    }

    __shared__ float sv[4];
    __shared__ int   si[4];
    if ((tid & 63) == 0) { sv[tid >> 6] = bv; si[tid >> 6] = bt; }
    __syncthreads();

    if (tid == 0) {
#pragma unroll
        for (int w = 1; w < 4; ++w)
            if (sv[w] > bv || (sv[w] == bv && si[w] < bt)) { bv = sv[w]; bt = si[w]; }
        out[pos] = bt;
    }
}

// ---------------------------------------------------------------------------
extern "C" void kernel_launch(void* const* d_in, const int* in_sizes, int n_in,
                              void* d_out, int out_size, void* d_ws, size_t ws_size,
                              hipStream_t stream)
{
    const int*   seq    = (const int*)d_in[0];     // (B, L) int32
    const float* conv_w = (const float*)d_in[1];   // (T, V, K) f32
    const float* conv_b = (const float*)d_in[2];   // (T,) f32
    int*         out    = (int*)d_out;             // (B, L) int32
    float*       wt     = (float*)d_ws;            // NROWS * T floats (~4.7 MB)

    transpose_w<<<Tt / 32, 256, 0, stream>>>(conv_w, conv_b, wt);
    conv_argmax<<<Bb * Ll, 256, 0, stream>>>(seq, wt, out);
}